// Round 2
// baseline (151.129 us; speedup 1.0000x reference)
//
#include <hip/hip_runtime.h>
#include <hip/hip_bf16.h>

// Problem constants
#define BB 16384
#define LL 9
#define DD 32
#define CR 128

typedef float v2 __attribute__((ext_vector_type(2)));

// ws layout (floats): A1[32][128], A2[32][128], WK[17][128]
// A1 = Wi@W1, A2 = Wj@W1, WK[k] = (relpos_row_k@Wr + br + bi + bj)@W1 + b1

__global__ void precomp_kernel(const float* __restrict__ relpos,
                               const float* __restrict__ Wi, const float* __restrict__ bi,
                               const float* __restrict__ Wj, const float* __restrict__ bj,
                               const float* __restrict__ Wr, const float* __restrict__ br,
                               const float* __restrict__ W1, const float* __restrict__ b1,
                               float* __restrict__ ws)
{
    __shared__ float rv[DD];
    float* A1 = ws;
    float* A2 = ws + DD * CR;
    float* WK = ws + 2 * DD * CR;

    const int c = threadIdx.x;   // 0..127
    const int blk = blockIdx.x;  // 0..80

    if (blk < 32) {
        const int d = blk;
        float s = 0.f;
        #pragma unroll
        for (int e = 0; e < DD; ++e) s = fmaf(Wi[d * DD + e], W1[e * CR + c], s);
        A1[d * CR + c] = s;
    } else if (blk < 64) {
        const int d = blk - 32;
        float s = 0.f;
        #pragma unroll
        for (int e = 0; e < DD; ++e) s = fmaf(Wj[d * DD + e], W1[e * CR + c], s);
        A2[d * CR + c] = s;
    } else {
        const int k = blk - 64;       // 0..16, dk = k-8 = i-j
        const int dk = k - 8;
        const int i = dk > 0 ? dk : 0;
        const int j = i - dk;
        if (c < DD) {
            float s = bi[c] + bj[c] + br[c];
            #pragma unroll
            for (int d = 0; d < DD; ++d)
                s = fmaf(relpos[(i * LL + j) * DD + d], Wr[d * DD + c], s);
            rv[c] = s;
        }
        __syncthreads();
        float s = b1[c];
        #pragma unroll
        for (int e = 0; e < DD; ++e) s = fmaf(rv[e], W1[e * CR + c], s);
        WK[k * CR + c] = s;
    }
}

// One wave handles batches with 2 adjacent channels per lane (c = 2*lane, 2*lane+1),
// all tables register-resident as packed float2; amdgpu_waves_per_eu(2,2) pins the
// allocator to the 256-VGPR budget so nothing spills to scratch.
__global__ __launch_bounds__(256)
__attribute__((amdgpu_waves_per_eu(2, 2)))
void outersum_main(const float* __restrict__ seq,
                   const float* __restrict__ ws,
                   const float* __restrict__ W2,
                   const float* __restrict__ b2,
                   float* __restrict__ out)
{
    const float* gA1 = ws;
    const float* gA2 = ws + DD * CR;
    const float* gWK = ws + 2 * DD * CR;

    const int lane = threadIdx.x & 63;
    const int wave = blockIdx.x * (blockDim.x >> 6) + (threadIdx.x >> 6);
    const int nw = (gridDim.x * blockDim.x) >> 6;
    const int cp = lane * 2;            // adjacent channel pair -> coalesced float2 loads

    // Register-resident tables (packed): 128 + 34 VGPRs.
    v2 a1[DD], a2[DD];
    #pragma unroll
    for (int d = 0; d < DD; ++d) {
        a1[d] = *(const v2*)(gA1 + d * CR + cp);
        a2[d] = *(const v2*)(gA2 + d * CR + cp);
    }
    v2 wk[17];
    #pragma unroll
    for (int k = 0; k < 17; ++k) wk[k] = *(const v2*)(gWK + k * CR + cp);

    // W2 rows for this lane's two channels: 4 consecutive floats.
    const float4 w4 = *(const float4*)(W2 + 2 * cp);
    v2 w2o0; w2o0.x = w4.x; w2o0.y = w4.z;   // W2[c0][0], W2[c1][0]
    v2 w2o1; w2o1.x = w4.y; w2o1.y = w4.w;   // W2[c0][1], W2[c1][1]
    const float bias0 = 81.f * b2[0];
    const float bias1 = 81.f * b2[1];

    for (int b = wave; b < BB; b += nw) {
        const int bu = __builtin_amdgcn_readfirstlane(b);
        const float* __restrict__ sp = seq + (size_t)bu * (LL * DD);

        // U/V: [9][2] packed GEMV against register tables; seq reads are
        // wave-uniform -> scalar loads.
        v2 U[LL], V[LL];
        #pragma unroll
        for (int i = 0; i < LL; ++i) {
            v2 u; u.x = 0.f; u.y = 0.f;
            v2 v; v.x = 0.f; v.y = 0.f;
            #pragma unroll
            for (int d = 0; d < DD; ++d) {
                const float s = sp[i * DD + d];
                v2 s2; s2.x = s; s2.y = s;
                u += s2 * a1[d];      // -ffp-contract=fast -> v_pk_fma_f32
                v += s2 * a2[d];
            }
            U[i] = u; V[i] = v;
        }

        // 81 outer-sum pairs, fully unrolled (static wk index k = i-j+8).
        v2 acc0; acc0.x = 0.f; acc0.y = 0.f;
        v2 acc1; acc1.x = 0.f; acc1.y = 0.f;
        #pragma unroll
        for (int i = 0; i < LL; ++i) {
            #pragma unroll
            for (int j = 0; j < LL; ++j) {
                v2 t = U[i] + V[j] + wk[i - j + 8];
                t.x = fmaxf(t.x, 0.f);
                t.y = fmaxf(t.y, 0.f);
                acc0 += t * w2o0;
                acc1 += t * w2o1;
            }
        }

        float r0 = acc0.x + acc0.y;
        float r1 = acc1.x + acc1.y;
        #pragma unroll
        for (int off = 32; off; off >>= 1) {
            r0 += __shfl_xor(r0, off, 64);
            r1 += __shfl_xor(r1, off, 64);
        }
        if (lane == 0) {
            float2 o; o.x = r0 + bias0; o.y = r1 + bias1;
            *(float2*)(out + (size_t)bu * 2) = o;
        }
    }
}

extern "C" void kernel_launch(void* const* d_in, const int* in_sizes, int n_in,
                              void* d_out, int out_size, void* d_ws, size_t ws_size,
                              hipStream_t stream)
{
    const float* seq    = (const float*)d_in[0];
    const float* relpos = (const float*)d_in[1];
    const float* Wi     = (const float*)d_in[2];
    const float* bi     = (const float*)d_in[3];
    const float* Wj     = (const float*)d_in[4];
    const float* bj     = (const float*)d_in[5];
    const float* Wr     = (const float*)d_in[6];
    const float* br     = (const float*)d_in[7];
    const float* W1     = (const float*)d_in[8];
    const float* b1     = (const float*)d_in[9];
    const float* W2     = (const float*)d_in[10];
    const float* b2     = (const float*)d_in[11];
    float* out = (float*)d_out;
    float* ws  = (float*)d_ws;

    precomp_kernel<<<81, 128, 0, stream>>>(relpos, Wi, bi, Wj, bj, Wr, br, W1, b1, ws);

    // 512 blocks x 4 waves = 2048 waves = exactly the resident capacity at
    // 2 waves/SIMD; 8 batches per wave via grid-stride.
    outersum_main<<<512, 256, 0, stream>>>(seq, ws, W2, b2, out);
}